// Round 7
// baseline (210.775 us; speedup 1.0000x reference)
//
#include <hip/hip_runtime.h>
#include <stdint.h>
#include <math.h>

#define EMBED 1024
#define HEADS 16
#define HDIM  64
#define SEQ   2048
#define BATCH 2

typedef __bf16 bf16x8 __attribute__((ext_vector_type(8)));
typedef float  f32x4  __attribute__((ext_vector_type(4)));
typedef unsigned short u16x8 __attribute__((ext_vector_type(8)));
typedef unsigned short u16x4 __attribute__((ext_vector_type(4)));
typedef uint32_t u32x4v __attribute__((ext_vector_type(4)));

static __device__ __forceinline__ unsigned short f2bf(float f){
  union { float f; uint32_t u; } v; v.f = f;
  uint32_t u = v.u;
  uint32_t r = (u + 0x7FFFu + ((u >> 16) & 1u)) >> 16;  // RNE
  return (unsigned short)r;
}
static __device__ __forceinline__ bf16x8 as_bf(u16x8 v){ return __builtin_bit_cast(bf16x8, v); }

static __device__ __forceinline__ uint32_t pk_bf16(float a, float b){
#if defined(__has_builtin) && __has_builtin(__builtin_amdgcn_cvt_pk_bf16_f32)
  typedef __bf16 bf16x2 __attribute__((ext_vector_type(2)));
  bf16x2 p = __builtin_amdgcn_cvt_pk_bf16_f32(a, b);
  return __builtin_bit_cast(uint32_t, p);
#else
  return (uint32_t)f2bf(a) | ((uint32_t)f2bf(b) << 16);
#endif
}

static __device__ __forceinline__ float fexp2(float x){
#if defined(__has_builtin) && __has_builtin(__builtin_amdgcn_exp2f)
  return __builtin_amdgcn_exp2f(x);
#else
  return exp2f(x);
#endif
}

// async global->LDS, 16B per lane. lp_wave must be WAVE-UNIFORM; HW adds lane*16.
static __device__ __forceinline__ void stage16(const unsigned short* gp,
                                               unsigned short* lp_wave, int lane){
#if defined(__has_builtin) && __has_builtin(__builtin_amdgcn_global_load_lds)
  __builtin_amdgcn_global_load_lds((const __attribute__((address_space(1))) void*)gp,
                                   (__attribute__((address_space(3))) void*)lp_wave,
                                   16, 0, 0);
#else
  *(u16x8*)(lp_wave + lane * 8) = *(const u16x8*)gp;
#endif
}

// ---------------- prep: cast x -> bf16, W_qkv -> wqkvT, W_out -> woutT --------------
__global__ __launch_bounds__(256) void prep(
    const float* __restrict__ x,      unsigned short* __restrict__ xb,
    const float* __restrict__ W_qkv,  unsigned short* __restrict__ wqkvT,
    const float* __restrict__ W_out,  unsigned short* __restrict__ woutT)
{
  __shared__ unsigned short T[32 * 36];
  const int bid = blockIdx.x;
  const int t   = threadIdx.x;

  if (bid < 4096){
    int i = (bid * 256 + t) * 4;
    float4 v = *(const float4*)(x + i);
    u16x4 o;
    o[0] = f2bf(v.x); o[1] = f2bf(v.y); o[2] = f2bf(v.z); o[3] = f2bf(v.w);
    *(u16x4*)(xb + i) = o;
    return;
  }
  const float* W; unsigned short* Wt; int N, n0, k0;
  if (bid < 7168){
    int idx = bid - 4096;
    W = W_qkv; Wt = wqkvT; N = 3072;
    n0 = (idx % 96) * 32; k0 = (idx / 96) * 32;
  } else {
    int idx = bid - 7168;
    W = W_out; Wt = woutT; N = 1024;
    n0 = (idx & 31) * 32; k0 = (idx >> 5) * 32;
  }
  int kr = t >> 3, nc = (t & 7) * 4;
  float4 wv = *(const float4*)(W + (size_t)(k0 + kr) * N + n0 + nc);
  T[(nc + 0) * 36 + kr] = f2bf(wv.x);
  T[(nc + 1) * 36 + kr] = f2bf(wv.y);
  T[(nc + 2) * 36 + kr] = f2bf(wv.z);
  T[(nc + 3) * 36 + kr] = f2bf(wv.w);
  __syncthreads();
  int nr = t >> 3, kc = (t & 7) * 4;
  *(u16x4*)(Wt + (size_t)(n0 + nr) * 1024 + k0 + kc) = *(const u16x4*)&T[nr * 36 + kc];
}

// ---------------- QKV GEMM body, BK=64, direct-VT for V (R6-proven) -----------------
static __device__ __forceinline__ void gemm_qkv_body(
    int bm, int bn, unsigned short* SM,
    const unsigned short* __restrict__ A,
    const unsigned short* __restrict__ Bt,
    const float* __restrict__ bias,
    unsigned short* __restrict__ q_ws,
    unsigned short* __restrict__ k_ws,
    unsigned short* __restrict__ vt_ws)
{
  unsigned short* As = SM;          // 128*64
  unsigned short* Bs = SM + 8192;   // 128*64
  const int K = 1024;
  const int tid  = threadIdx.x;
  const int w    = tid >> 6, lane = tid & 63;
  const int quad = lane >> 4, l16 = lane & 15;
  const int wm   = (w >> 1) * 64, wn = (w & 1) * 64;

  f32x4 acc[4][4] = {};

  for (int k0 = 0; k0 < K; k0 += 64) {
    #pragma unroll
    for (int i = 0; i < 4; i++){
      int c = w * 4 + i;
      int row = c * 8 + (lane >> 3);
      int kg = (lane & 7) ^ (row & 7);
      stage16(A  + (size_t)(bm * 128 + row) * K + k0 + kg * 8, As + c * 512, lane);
      stage16(Bt + (size_t)(bn * 128 + row) * K + k0 + kg * 8, Bs + c * 512, lane);
    }
    __syncthreads();

    #pragma unroll
    for (int kk = 0; kk < 2; kk++){
      bf16x8 af[4], bfr[4];
      #pragma unroll
      for (int t = 0; t < 4; t++){
        int ra = wm + t * 16 + l16;
        int rb = wn + t * 16 + l16;
        af[t]  = as_bf(*(const u16x8*)&As[(ra << 6) + ((((kk << 2) + quad) ^ (ra & 7)) << 3)]);
        bfr[t] = as_bf(*(const u16x8*)&Bs[(rb << 6) + ((((kk << 2) + quad) ^ (rb & 7)) << 3)]);
      }
      #pragma unroll
      for (int mt = 0; mt < 4; mt++)
        #pragma unroll
        for (int nt = 0; nt < 4; nt++)
          acc[mt][nt] = __builtin_amdgcn_mfma_f32_16x16x32_bf16(af[mt], bfr[nt], acc[mt][nt], 0, 0, 0);
    }
    __syncthreads();
  }

  const int which = (bn * 128) >> 10;   // 0=Q 1=K 2=V
  const int b = bm >> 4;
  const int S_base = (bm & 15) * 128 + wm;

  if (which == 2){
    #pragma unroll
    for (int nt = 0; nt < 4; nt++){
      int gnb = bn * 128 + wn + nt * 16;
      int h   = (gnb & 1023) >> 6;
      int d   = (gnb & 63) + l16;
      float bv = bias[gnb + l16];
      unsigned short* vp = vt_ws + (size_t)(b * HEADS + h) * SEQ * HDIM + (size_t)d * SEQ;
      #pragma unroll
      for (int mt = 0; mt < 4; mt++){
        int spos = S_base + (mt >> 1) * 32 + quad * 8 + (mt & 1) * 4;
        u16x4 o4;
        #pragma unroll
        for (int r = 0; r < 4; r++) o4[r] = f2bf(acc[mt][nt][r] + bv);
        *(u16x4*)(vp + spos) = o4;
      }
    }
    return;
  }

  unsigned short* dst = (which == 0) ? q_ws : k_ws;
  const float scale = (which == 0) ? 0.18033688f : 1.0f;  // Q: 1/sqrt(Hd)*log2(e)
  #pragma unroll
  for (int nt = 0; nt < 4; nt++){
    int gnb = bn * 128 + wn + nt * 16;
    int h   = (gnb & 1023) >> 6;
    int hd  = (gnb & 63) + l16;
    float bv = bias[gnb + l16];
    unsigned short* dp = dst + (size_t)(b * HEADS + h) * SEQ * HDIM + hd;
    #pragma unroll
    for (int mt = 0; mt < 4; mt++){
      int s0 = S_base + mt * 16 + quad * 4;
      #pragma unroll
      for (int r = 0; r < 4; r++)
        dp[(size_t)(s0 + r) * HDIM] = f2bf((acc[mt][nt][r] + bv) * scale);
    }
  }
}

// ---------------- out-proj GEMM body, BK=64: BM=128, BN=64 --------------------------
static __device__ __forceinline__ void gemm_out_body(
    int bm, int bn, unsigned short* SM,
    const unsigned short* __restrict__ A,
    const unsigned short* __restrict__ Bt,
    const float* __restrict__ bias,
    float* __restrict__ Cout)
{
  unsigned short* As = SM;          // 128*64
  unsigned short* Bs = SM + 8192;   // 64*64
  const int K = 1024, N = 1024;
  const int tid  = threadIdx.x;
  const int w    = tid >> 6, lane = tid & 63;
  const int quad = lane >> 4, l16 = lane & 15;
  const int wm   = (w >> 1) * 64, wn = (w & 1) * 32;

  f32x4 acc[4][2] = {};

  for (int k0 = 0; k0 < K; k0 += 64) {
    #pragma unroll
    for (int i = 0; i < 4; i++){
      int c = w * 4 + i;
      int row = c * 8 + (lane >> 3);
      int kg = (lane & 7) ^ (row & 7);
      stage16(A + (size_t)(bm * 128 + row) * K + k0 + kg * 8, As + c * 512, lane);
    }
    #pragma unroll
    for (int i = 0; i < 2; i++){
      int c = w * 2 + i;
      int row = c * 8 + (lane >> 3);
      int kg = (lane & 7) ^ (row & 7);
      stage16(Bt + (size_t)(bn * 64 + row) * K + k0 + kg * 8, Bs + c * 512, lane);
    }
    __syncthreads();

    #pragma unroll
    for (int kk = 0; kk < 2; kk++){
      bf16x8 af[4], bfr[2];
      #pragma unroll
      for (int t = 0; t < 4; t++){
        int ra = wm + t * 16 + l16;
        af[t] = as_bf(*(const u16x8*)&As[(ra << 6) + ((((kk << 2) + quad) ^ (ra & 7)) << 3)]);
      }
      #pragma unroll
      for (int t = 0; t < 2; t++){
        int rb = wn + t * 16 + l16;
        bfr[t] = as_bf(*(const u16x8*)&Bs[(rb << 6) + ((((kk << 2) + quad) ^ (rb & 7)) << 3)]);
      }
      #pragma unroll
      for (int mt = 0; mt < 4; mt++)
        #pragma unroll
        for (int nt = 0; nt < 2; nt++)
          acc[mt][nt] = __builtin_amdgcn_mfma_f32_16x16x32_bf16(af[mt], bfr[nt], acc[mt][nt], 0, 0, 0);
    }
    __syncthreads();
  }

  #pragma unroll
  for (int mt = 0; mt < 4; mt++)
    #pragma unroll
    for (int nt = 0; nt < 2; nt++)
      #pragma unroll
      for (int r = 0; r < 4; r++){
        int gm = bm * 128 + wm + mt * 16 + quad * 4 + r;
        int gn = bn * 64 + wn + nt * 16 + l16;
        Cout[(size_t)gm * N + gn] = acc[mt][nt][r] + bias[gn];
      }
}

// ---------------- flash attention body: mq=2, QBLK=128, 4 waves, Q-direct -----------
// R1/R2-proven math (bitwise-identical accumulation order), R6-proven Q-direct +
// reg-prefetch dbuf. 32KB LDS (K/V dbuf). Processes 16 bh starting at bh_base.
static __device__ __forceinline__ void attn_body(
    int abid, int bh_base, unsigned short* SM,
    const unsigned short* __restrict__ q_ws,
    const unsigned short* __restrict__ k_ws,
    const unsigned short* __restrict__ vt_ws,
    unsigned short* __restrict__ o_ws)
{
  unsigned short* Ks  = SM;           // [2][64*64]
  unsigned short* VTs = SM + 8192;    // [2][64*64]
  const int tid  = threadIdx.x;
  const int bh   = bh_base + (abid >> 4);
  const int qt   = abid & 15;          // 128-row Q tile
  const int w    = tid >> 6, lane = tid & 63;
  const int quad = lane >> 4, l16 = lane & 15;
  const size_t base = (size_t)bh * SEQ * HDIM;

  bf16x8 bq[2][2];
  #pragma unroll
  for (int mq = 0; mq < 2; mq++){
    int qrow = qt * 128 + w * 32 + mq * 16 + l16;
    #pragma unroll
    for (int ks = 0; ks < 2; ks++)
      bq[mq][ks] = as_bf(*(const u16x8*)(q_ws + base + (size_t)qrow * HDIM + (ks * 4 + quad) * 8));
  }

  const int row0 = w * 16 + (lane >> 3), row1 = row0 + 8;
  const int kg0 = (lane & 7) ^ (row0 & 7), kg1 = (lane & 7) ^ (row1 & 7);
  const int dofs0 = (w * 2) * 512 + lane * 8, dofs1 = dofs0 + 512;

  stage16(k_ws  + base + (size_t)row0 * HDIM + kg0 * 8, Ks  + (w * 2) * 512,     lane);
  stage16(k_ws  + base + (size_t)row1 * HDIM + kg1 * 8, Ks  + (w * 2 + 1) * 512, lane);
  stage16(vt_ws + base + (size_t)row0 * SEQ + kg0 * 8,  VTs + (w * 2) * 512,     lane);
  stage16(vt_ws + base + (size_t)row1 * SEQ + kg1 * 8,  VTs + (w * 2 + 1) * 512, lane);
  __syncthreads();

  const unsigned short* kp0 = k_ws  + base + (size_t)(64 + row0) * HDIM + kg0 * 8;
  const unsigned short* kp1 = k_ws  + base + (size_t)(64 + row1) * HDIM + kg1 * 8;
  const unsigned short* vp0 = vt_ws + base + (size_t)row0 * SEQ + 64 + kg0 * 8;
  const unsigned short* vp1 = vt_ws + base + (size_t)row1 * SEQ + 64 + kg1 * 8;

  f32x4 acc[2][4] = {};
  float li[2] = {0.f, 0.f};

  for (int kt = 0; kt < SEQ / 64; kt++){
    const int co = (kt & 1) * 4096;
    u16x8 kpre0, kpre1, vpre0, vpre1;
    if (kt < SEQ / 64 - 1){
      kpre0 = *(const u16x8*)kp0;  kp0 += 64 * HDIM;
      kpre1 = *(const u16x8*)kp1;  kp1 += 64 * HDIM;
      vpre0 = *(const u16x8*)vp0;  vp0 += 64;
      vpre1 = *(const u16x8*)vp1;  vp1 += 64;
    }

    f32x4 sf[4][2] = {};
    #pragma unroll
    for (int ks = 0; ks < 2; ks++)
      #pragma unroll
      for (int nt = 0; nt < 4; nt++){
        int rk = nt * 16 + l16;
        bf16x8 ak = as_bf(*(const u16x8*)&Ks[co + (rk << 6) + ((((ks << 2) + quad) ^ (rk & 7)) << 3)]);
        #pragma unroll
        for (int mq = 0; mq < 2; mq++)
          sf[nt][mq] = __builtin_amdgcn_mfma_f32_16x16x32_bf16(ak, bq[mq][ks], sf[nt][mq], 0, 0, 0);
      }

    #pragma unroll
    for (int nt = 0; nt < 4; nt++)
      #pragma unroll
      for (int mq = 0; mq < 2; mq++)
        #pragma unroll
        for (int r = 0; r < 4; r++)
          sf[nt][mq][r] = fexp2(sf[nt][mq][r]);
    #pragma unroll
    for (int mq = 0; mq < 2; mq++)
      #pragma unroll
      for (int nt = 0; nt < 4; nt++)
        li[mq] += (sf[nt][mq][0] + sf[nt][mq][1]) + (sf[nt][mq][2] + sf[nt][mq][3]);

    #pragma unroll
    for (int c = 0; c < 2; c++){
      bf16x8 ap[2];
      #pragma unroll
      for (int mq = 0; mq < 2; mq++){
        u32x4v aw;
        aw[0] = pk_bf16(sf[c * 2][mq][0],     sf[c * 2][mq][1]);
        aw[1] = pk_bf16(sf[c * 2][mq][2],     sf[c * 2][mq][3]);
        aw[2] = pk_bf16(sf[c * 2 + 1][mq][0], sf[c * 2 + 1][mq][1]);
        aw[3] = pk_bf16(sf[c * 2 + 1][mq][2], sf[c * 2 + 1][mq][3]);
        ap[mq] = __builtin_bit_cast(bf16x8, aw);
      }
      #pragma unroll
      for (int nt = 0; nt < 4; nt++){
        int rv = nt * 16 + l16;
        bf16x8 bv = as_bf(*(const u16x8*)&VTs[co + (rv << 6) + ((((c << 2) + quad) ^ (rv & 7)) << 3)]);
        #pragma unroll
        for (int mq = 0; mq < 2; mq++)
          acc[mq][nt] = __builtin_amdgcn_mfma_f32_16x16x32_bf16(ap[mq], bv, acc[mq][nt], 0, 0, 0);
      }
    }

    if (kt < SEQ / 64 - 1){
      const int no = (co ^ 4096);
      *(u16x8*)&Ks[no + dofs0]  = kpre0;
      *(u16x8*)&Ks[no + dofs1]  = kpre1;
      *(u16x8*)&VTs[no + dofs0] = vpre0;
      *(u16x8*)&VTs[no + dofs1] = vpre1;
    }
    __syncthreads();
  }

  #pragma unroll
  for (int mq = 0; mq < 2; mq++){
    li[mq] += __shfl_xor(li[mq], 16);
    li[mq] += __shfl_xor(li[mq], 32);
  }
  float inv[2] = {1.0f / li[0], 1.0f / li[1]};
  float invr[2][4];
  #pragma unroll
  for (int mq = 0; mq < 2; mq++)
    #pragma unroll
    for (int r = 0; r < 4; r++)
      invr[mq][r] = __shfl(inv[mq], quad * 4 + r);

  int b = bh >> 4, h = bh & 15;
  #pragma unroll
  for (int mq = 0; mq < 2; mq++)
    #pragma unroll
    for (int nt = 0; nt < 4; nt++)
      #pragma unroll
      for (int r = 0; r < 4; r++){
        int s = qt * 128 + w * 32 + mq * 16 + quad * 4 + r;
        int d = h * 64 + nt * 16 + l16;
        o_ws[((size_t)(b * SEQ + s)) * EMBED + d] = f2bf(acc[mq][nt][r] * invr[mq][r]);
      }
}

// ---------------- dispatch wrappers -------------------------------------------------
__global__ __launch_bounds__(256) void qkv_part(
    const unsigned short* __restrict__ A, const unsigned short* __restrict__ Bt,
    const float* __restrict__ bias,
    unsigned short* q, unsigned short* k, unsigned short* vt, int bm_base)
{
  __shared__ unsigned short SM[16384];
  gemm_qkv_body(bm_base + (blockIdx.x & 15), blockIdx.x >> 4, SM, A, Bt, bias, q, k, vt);
}

__global__ __launch_bounds__(256) void out_part(
    const unsigned short* __restrict__ A, const unsigned short* __restrict__ Bt,
    const float* __restrict__ bias, float* C, int bm_base)
{
  __shared__ unsigned short SM[16384];
  gemm_out_body(bm_base + (blockIdx.x & 15), blockIdx.x >> 4, SM, A, Bt, bias, C);
}

// combo1: attn for bh 0..15 (blocks 0..255) CONCURRENT with qkv for b=1 (blocks 256..639).
// Disjoint data: attn reads q/k/vt[bh<16], writes o bytes [0,4M); gemm reads xb bytes
// [4M,8M) (aliased region, disjoint halves), writes q/k/vt[bh>=16].
__global__ __launch_bounds__(256) void combo_attn0_qkv1(
    const unsigned short* __restrict__ xb, const unsigned short* __restrict__ wqkvT,
    const float* __restrict__ b_qkv,
    unsigned short* q, unsigned short* k, unsigned short* vt, unsigned short* o)
{
  __shared__ unsigned short SM[16384];
  if (blockIdx.x < 256)
    attn_body(blockIdx.x, 0, SM, q, k, vt, o);
  else {
    int g = blockIdx.x - 256;
    gemm_qkv_body(16 + (g & 15), g >> 4, SM, xb, wqkvT, b_qkv, q, k, vt);
  }
}

// combo2: attn for bh 16..31 (writes o rows b=1) CONCURRENT with out-proj for b=0
// (reads o rows b=0, written by combo1). Disjoint row ranges.
__global__ __launch_bounds__(256) void combo_attn1_out0(
    const unsigned short* __restrict__ q, const unsigned short* __restrict__ k,
    const unsigned short* __restrict__ vt, unsigned short* o,
    const unsigned short* __restrict__ woutT, const float* __restrict__ b_out,
    float* out)
{
  __shared__ unsigned short SM[16384];
  if (blockIdx.x < 256)
    attn_body(blockIdx.x, 16, SM, q, k, vt, o);
  else {
    int g = blockIdx.x - 256;
    gemm_out_body(g & 15, g >> 4, SM, o, woutT, b_out, out);
  }
}

// ---------------- launch ----------------
// ws alias table (40 MB):
//   [0,8M)   xb (prep-w; qkv reads [0,4M) in S2, [4M,8M) in S3) ->
//            o  (attn-w: [0,4M) in S3, [4M,8M) in S4; gemm_out reads S4/S5)
//   [8,16M)  q      [16,24M) k     [24,32M) vt
//   [32,38M) wqkvT  [38,40M) woutT
// Batch-pipelined: prep -> qkv(b0) -> {attn(b0) || qkv(b1)} -> {attn(b1) || out(b0)} -> out(b1)
extern "C" void kernel_launch(void* const* d_in, const int* in_sizes, int n_in,
                              void* d_out, int out_size, void* d_ws, size_t ws_size,
                              hipStream_t stream) {
  const float* x     = (const float*)d_in[0];
  const float* W_qkv = (const float*)d_in[1];
  const float* b_qkv = (const float*)d_in[2];
  const float* W_out = (const float*)d_in[3];
  const float* b_out = (const float*)d_in[4];
  float* out = (float*)d_out;

  char* ws = (char*)d_ws;
  unsigned short* xb    = (unsigned short*)(ws);
  unsigned short* o     = (unsigned short*)(ws);                      // aliases xb (disjoint halves in time)
  unsigned short* q     = (unsigned short*)(ws + ((size_t)8  << 20));
  unsigned short* k     = (unsigned short*)(ws + ((size_t)16 << 20));
  unsigned short* vt    = (unsigned short*)(ws + ((size_t)24 << 20));
  unsigned short* wqkvT = (unsigned short*)(ws + ((size_t)32 << 20));
  unsigned short* woutT = (unsigned short*)(ws + ((size_t)38 << 20));

  prep<<<dim3(8192), dim3(256), 0, stream>>>(x, xb, W_qkv, wqkvT, W_out, woutT);

  qkv_part<<<dim3(384), dim3(256), 0, stream>>>(xb, wqkvT, b_qkv, q, k, vt, 0);

  combo_attn0_qkv1<<<dim3(640), dim3(256), 0, stream>>>(xb, wqkvT, b_qkv, q, k, vt, o);

  combo_attn1_out0<<<dim3(512), dim3(256), 0, stream>>>(q, k, vt, o, woutT, b_out, out);

  out_part<<<dim3(256), dim3(256), 0, stream>>>(o, woutT, b_out, out, 16);
}

// Round 8
// 197.904 us; speedup vs baseline: 1.0650x; 1.0650x over previous
//
#include <hip/hip_runtime.h>
#include <stdint.h>
#include <math.h>

#define EMBED 1024
#define HEADS 16
#define HDIM  64
#define SEQ   2048
#define BATCH 2

typedef __bf16 bf16x8 __attribute__((ext_vector_type(8)));
typedef float  f32x4  __attribute__((ext_vector_type(4)));
typedef unsigned short u16x8 __attribute__((ext_vector_type(8)));
typedef unsigned short u16x4 __attribute__((ext_vector_type(4)));
typedef uint32_t u32x4v __attribute__((ext_vector_type(4)));

static __device__ __forceinline__ unsigned short f2bf(float f){
  union { float f; uint32_t u; } v; v.f = f;
  uint32_t u = v.u;
  uint32_t r = (u + 0x7FFFu + ((u >> 16) & 1u)) >> 16;  // RNE
  return (unsigned short)r;
}
static __device__ __forceinline__ bf16x8 as_bf(u16x8 v){ return __builtin_bit_cast(bf16x8, v); }

static __device__ __forceinline__ uint32_t pk_bf16(float a, float b){
#if defined(__has_builtin) && __has_builtin(__builtin_amdgcn_cvt_pk_bf16_f32)
  typedef __bf16 bf16x2 __attribute__((ext_vector_type(2)));
  bf16x2 p = __builtin_amdgcn_cvt_pk_bf16_f32(a, b);
  return __builtin_bit_cast(uint32_t, p);
#else
  return (uint32_t)f2bf(a) | ((uint32_t)f2bf(b) << 16);
#endif
}

static __device__ __forceinline__ float fexp2(float x){
#if defined(__has_builtin) && __has_builtin(__builtin_amdgcn_exp2f)
  return __builtin_amdgcn_exp2f(x);
#else
  return exp2f(x);
#endif
}

// async global->LDS, 16B per lane. lp_wave must be WAVE-UNIFORM; HW adds lane*16.
static __device__ __forceinline__ void stage16(const unsigned short* gp,
                                               unsigned short* lp_wave, int lane){
#if defined(__has_builtin) && __has_builtin(__builtin_amdgcn_global_load_lds)
  __builtin_amdgcn_global_load_lds((const __attribute__((address_space(1))) void*)gp,
                                   (__attribute__((address_space(3))) void*)lp_wave,
                                   16, 0, 0);
#else
  *(u16x8*)(lp_wave + lane * 8) = *(const u16x8*)gp;
#endif
}

// ---------------- prep: cast x -> bf16, W_qkv -> wqkvT, W_out -> woutT --------------
__global__ __launch_bounds__(256) void prep(
    const float* __restrict__ x,      unsigned short* __restrict__ xb,
    const float* __restrict__ W_qkv,  unsigned short* __restrict__ wqkvT,
    const float* __restrict__ W_out,  unsigned short* __restrict__ woutT)
{
  __shared__ unsigned short T[32 * 36];
  const int bid = blockIdx.x;
  const int t   = threadIdx.x;

  if (bid < 4096){
    int i = (bid * 256 + t) * 4;
    float4 v = *(const float4*)(x + i);
    u16x4 o;
    o[0] = f2bf(v.x); o[1] = f2bf(v.y); o[2] = f2bf(v.z); o[3] = f2bf(v.w);
    *(u16x4*)(xb + i) = o;
    return;
  }
  const float* W; unsigned short* Wt; int N, n0, k0;
  if (bid < 7168){
    int idx = bid - 4096;
    W = W_qkv; Wt = wqkvT; N = 3072;
    n0 = (idx % 96) * 32; k0 = (idx / 96) * 32;
  } else {
    int idx = bid - 7168;
    W = W_out; Wt = woutT; N = 1024;
    n0 = (idx & 31) * 32; k0 = (idx >> 5) * 32;
  }
  int kr = t >> 3, nc = (t & 7) * 4;
  float4 wv = *(const float4*)(W + (size_t)(k0 + kr) * N + n0 + nc);
  T[(nc + 0) * 36 + kr] = f2bf(wv.x);
  T[(nc + 1) * 36 + kr] = f2bf(wv.y);
  T[(nc + 2) * 36 + kr] = f2bf(wv.z);
  T[(nc + 3) * 36 + kr] = f2bf(wv.w);
  __syncthreads();
  int nr = t >> 3, kc = (t & 7) * 4;
  *(u16x4*)(Wt + (size_t)(n0 + nr) * 1024 + k0 + kc) = *(const u16x4*)&T[nr * 36 + kc];
}

// ---------------- QKV GEMM, BK=64; V written DIRECTLY in VT layout (R6-proven) ------
__global__ __launch_bounds__(256) void gemm_qkv(
    const unsigned short* __restrict__ A,
    const unsigned short* __restrict__ Bt,
    const float* __restrict__ bias,
    unsigned short* __restrict__ q_ws,
    unsigned short* __restrict__ k_ws,
    unsigned short* __restrict__ vt_ws,
    int M, int N, int K)
{
  __shared__ unsigned short As[128 * 64];   // 16KB
  __shared__ unsigned short Bs[128 * 64];   // 16KB
  const int tid  = threadIdx.x;
  const int bm   = blockIdx.x, bn = blockIdx.y;
  const int w    = tid >> 6, lane = tid & 63;
  const int quad = lane >> 4, l16 = lane & 15;
  const int wm   = (w >> 1) * 64, wn = (w & 1) * 64;

  f32x4 acc[4][4] = {};

  for (int k0 = 0; k0 < K; k0 += 64) {
    #pragma unroll
    for (int i = 0; i < 4; i++){
      int c = w * 4 + i;
      int row = c * 8 + (lane >> 3);
      int kg = (lane & 7) ^ (row & 7);
      stage16(A  + (size_t)(bm * 128 + row) * K + k0 + kg * 8, &As[c * 512], lane);
      stage16(Bt + (size_t)(bn * 128 + row) * K + k0 + kg * 8, &Bs[c * 512], lane);
    }
    __syncthreads();

    #pragma unroll
    for (int kk = 0; kk < 2; kk++){
      bf16x8 af[4], bfr[4];
      #pragma unroll
      for (int t = 0; t < 4; t++){
        int ra = wm + t * 16 + l16;
        int rb = wn + t * 16 + l16;
        af[t]  = as_bf(*(const u16x8*)&As[(ra << 6) + ((((kk << 2) + quad) ^ (ra & 7)) << 3)]);
        bfr[t] = as_bf(*(const u16x8*)&Bs[(rb << 6) + ((((kk << 2) + quad) ^ (rb & 7)) << 3)]);
      }
      #pragma unroll
      for (int mt = 0; mt < 4; mt++)
        #pragma unroll
        for (int nt = 0; nt < 4; nt++)
          acc[mt][nt] = __builtin_amdgcn_mfma_f32_16x16x32_bf16(af[mt], bfr[nt], acc[mt][nt], 0, 0, 0);
    }
    __syncthreads();
  }

  const int which = (bn * 128) >> 10;   // block-uniform: 0=Q 1=K 2=V
  const int b = bm >> 4;
  const int S_base = (bm & 15) * 128 + wm;

  if (which == 2){
    #pragma unroll
    for (int nt = 0; nt < 4; nt++){
      int gnb = bn * 128 + wn + nt * 16;
      int h   = (gnb & 1023) >> 6;
      int d   = (gnb & 63) + l16;
      float bv = bias[gnb + l16];
      unsigned short* vp = vt_ws + (size_t)(b * HEADS + h) * SEQ * HDIM + (size_t)d * SEQ;
      #pragma unroll
      for (int mt = 0; mt < 4; mt++){
        int spos = S_base + (mt >> 1) * 32 + quad * 8 + (mt & 1) * 4;
        u16x4 o4;
        #pragma unroll
        for (int r = 0; r < 4; r++) o4[r] = f2bf(acc[mt][nt][r] + bv);
        *(u16x4*)(vp + spos) = o4;
      }
    }
    return;
  }

  unsigned short* dst = (which == 0) ? q_ws : k_ws;
  const float scale = (which == 0) ? 0.18033688f : 1.0f;  // Q: 1/sqrt(Hd)*log2(e)
  #pragma unroll
  for (int nt = 0; nt < 4; nt++){
    int gnb = bn * 128 + wn + nt * 16;
    int h   = (gnb & 1023) >> 6;
    int hd  = (gnb & 63) + l16;
    float bv = bias[gnb + l16];
    unsigned short* dp = dst + (size_t)(b * HEADS + h) * SEQ * HDIM + hd;
    #pragma unroll
    for (int mt = 0; mt < 4; mt++){
      int s0 = S_base + mt * 16 + quad * 4;
      #pragma unroll
      for (int r = 0; r < 4; r++)
        dp[(size_t)(s0 + r) * HDIM] = f2bf((acc[mt][nt][r] + bv) * scale);
    }
  }
}

// ---------------- out-proj GEMM, BK=64: BM=128, BN=64 -------------------------------
__global__ __launch_bounds__(256) void gemm_out(
    const unsigned short* __restrict__ A,
    const unsigned short* __restrict__ Bt,
    const float* __restrict__ bias,
    float* __restrict__ Cout,
    int M, int N, int K)
{
  __shared__ unsigned short As[128 * 64];   // 16KB
  __shared__ unsigned short Bs[64 * 64];    // 8KB
  const int tid  = threadIdx.x;
  const int bm   = blockIdx.x, bn = blockIdx.y;
  const int w    = tid >> 6, lane = tid & 63;
  const int quad = lane >> 4, l16 = lane & 15;
  const int wm   = (w >> 1) * 64, wn = (w & 1) * 32;

  f32x4 acc[4][2] = {};

  for (int k0 = 0; k0 < K; k0 += 64) {
    #pragma unroll
    for (int i = 0; i < 4; i++){
      int c = w * 4 + i;
      int row = c * 8 + (lane >> 3);
      int kg = (lane & 7) ^ (row & 7);
      stage16(A + (size_t)(bm * 128 + row) * K + k0 + kg * 8, &As[c * 512], lane);
    }
    #pragma unroll
    for (int i = 0; i < 2; i++){
      int c = w * 2 + i;
      int row = c * 8 + (lane >> 3);
      int kg = (lane & 7) ^ (row & 7);
      stage16(Bt + (size_t)(bn * 64 + row) * K + k0 + kg * 8, &Bs[c * 512], lane);
    }
    __syncthreads();

    #pragma unroll
    for (int kk = 0; kk < 2; kk++){
      bf16x8 af[4], bfr[2];
      #pragma unroll
      for (int t = 0; t < 4; t++){
        int ra = wm + t * 16 + l16;
        af[t] = as_bf(*(const u16x8*)&As[(ra << 6) + ((((kk << 2) + quad) ^ (ra & 7)) << 3)]);
      }
      #pragma unroll
      for (int t = 0; t < 2; t++){
        int rb = wn + t * 16 + l16;
        bfr[t] = as_bf(*(const u16x8*)&Bs[(rb << 6) + ((((kk << 2) + quad) ^ (rb & 7)) << 3)]);
      }
      #pragma unroll
      for (int mt = 0; mt < 4; mt++)
        #pragma unroll
        for (int nt = 0; nt < 2; nt++)
          acc[mt][nt] = __builtin_amdgcn_mfma_f32_16x16x32_bf16(af[mt], bfr[nt], acc[mt][nt], 0, 0, 0);
    }
    __syncthreads();
  }

  #pragma unroll
  for (int mt = 0; mt < 4; mt++)
    #pragma unroll
    for (int nt = 0; nt < 2; nt++)
      #pragma unroll
      for (int r = 0; r < 4; r++){
        int gm = bm * 128 + wm + mt * 16 + quad * 4 + r;
        int gn = bn * 64 + wn + nt * 16 + l16;
        Cout[(size_t)gm * N + gn] = acc[mt][nt][r] + bias[gn];
      }
}

// ---------------- flash attention, intra-block KV split -----------------------------
// R7 finding: attn wall ~= 32 tiles x 1.7us serial chain per block, invariant to
// occupancy/work. Halve the chain: 512-thread block = two 4-wave groups; group g
// owns KV rows [g*1024, g*1024+1024) = 16 tiles, with its OWN 32KB K/V dbuf.
// Block-wide barrier keeps the two equal-length pipelines in lockstep. No running
// max in this softmax -> partials combine EXACTLY (acc0+acc1, li0+li1) via LDS
// reuse after the loop. Grid 512 blocks x 64KB LDS = 2 blocks/CU, 16 waves/CU.
__global__ __launch_bounds__(512) void attn(
    const unsigned short* __restrict__ q_ws,
    const unsigned short* __restrict__ k_ws,
    const unsigned short* __restrict__ vt_ws,
    unsigned short* __restrict__ o_ws)
{
  __shared__ unsigned short SM[32768];         // 64KB: [grp][Ks 2x64x64 | VTs 2x64x64]
  const int tid  = threadIdx.x;
  const int wgid = blockIdx.x;                 // [0,512)
  const int lin  = (wgid & 7) * 64 + (wgid >> 3);   // XCD x owns bh [4x,4x+4)
  const int bh   = lin >> 4, qt = lin & 15;    // qt in [0,16): 128-row Q tile
  const int grp  = tid >> 8;                   // KV segment 0/1 (wave-uniform)
  const int w    = (tid >> 6) & 3, lane = tid & 63;
  const int quad = lane >> 4, l16 = lane & 15;
  const size_t base = (size_t)bh * SEQ * HDIM;
  unsigned short* Ks  = SM + grp * 16384;
  unsigned short* VTs = Ks + 8192;
  const int kvb = grp * 1024;                  // this group's first kv row

  // Q fragments direct to regs (both groups read the same Q tile)
  bf16x8 bq[2][2];
  #pragma unroll
  for (int mq = 0; mq < 2; mq++){
    int qrow = qt * 128 + w * 32 + mq * 16 + l16;
    #pragma unroll
    for (int ks = 0; ks < 2; ks++)
      bq[mq][ks] = as_bf(*(const u16x8*)(q_ws + base + (size_t)qrow * HDIM + (ks * 4 + quad) * 8));
  }

  const int row0 = w * 16 + (lane >> 3), row1 = row0 + 8;
  const int kg0 = (lane & 7) ^ (row0 & 7), kg1 = (lane & 7) ^ (row1 & 7);
  const int dofs0 = (w * 2) * 512 + lane * 8, dofs1 = dofs0 + 512;

  stage16(k_ws  + base + (size_t)(kvb + row0) * HDIM + kg0 * 8, Ks  + (w * 2) * 512,     lane);
  stage16(k_ws  + base + (size_t)(kvb + row1) * HDIM + kg1 * 8, Ks  + (w * 2 + 1) * 512, lane);
  stage16(vt_ws + base + (size_t)row0 * SEQ + kvb + kg0 * 8,    VTs + (w * 2) * 512,     lane);
  stage16(vt_ws + base + (size_t)row1 * SEQ + kvb + kg1 * 8,    VTs + (w * 2 + 1) * 512, lane);
  __syncthreads();

  const unsigned short* kp0 = k_ws  + base + (size_t)(kvb + 64 + row0) * HDIM + kg0 * 8;
  const unsigned short* kp1 = k_ws  + base + (size_t)(kvb + 64 + row1) * HDIM + kg1 * 8;
  const unsigned short* vp0 = vt_ws + base + (size_t)row0 * SEQ + kvb + 64 + kg0 * 8;
  const unsigned short* vp1 = vt_ws + base + (size_t)row1 * SEQ + kvb + 64 + kg1 * 8;

  f32x4 acc[2][4] = {};
  float li[2] = {0.f, 0.f};

  for (int kt = 0; kt < 16; kt++){
    const int co = (kt & 1) * 4096;
    u16x8 kpre0, kpre1, vpre0, vpre1;
    if (kt < 15){
      kpre0 = *(const u16x8*)kp0;  kp0 += 64 * HDIM;
      kpre1 = *(const u16x8*)kp1;  kp1 += 64 * HDIM;
      vpre0 = *(const u16x8*)vp0;  vp0 += 64;
      vpre1 = *(const u16x8*)vp1;  vp1 += 64;
    }

    f32x4 sf[4][2] = {};
    #pragma unroll
    for (int ks = 0; ks < 2; ks++)
      #pragma unroll
      for (int nt = 0; nt < 4; nt++){
        int rk = nt * 16 + l16;
        bf16x8 ak = as_bf(*(const u16x8*)&Ks[co + (rk << 6) + ((((ks << 2) + quad) ^ (rk & 7)) << 3)]);
        #pragma unroll
        for (int mq = 0; mq < 2; mq++)
          sf[nt][mq] = __builtin_amdgcn_mfma_f32_16x16x32_bf16(ak, bq[mq][ks], sf[nt][mq], 0, 0, 0);
      }

    #pragma unroll
    for (int nt = 0; nt < 4; nt++)
      #pragma unroll
      for (int mq = 0; mq < 2; mq++)
        #pragma unroll
        for (int r = 0; r < 4; r++)
          sf[nt][mq][r] = fexp2(sf[nt][mq][r]);
    #pragma unroll
    for (int mq = 0; mq < 2; mq++)
      #pragma unroll
      for (int nt = 0; nt < 4; nt++)
        li[mq] += (sf[nt][mq][0] + sf[nt][mq][1]) + (sf[nt][mq][2] + sf[nt][mq][3]);

    #pragma unroll
    for (int c = 0; c < 2; c++){
      bf16x8 ap[2];
      #pragma unroll
      for (int mq = 0; mq < 2; mq++){
        u32x4v aw;
        aw[0] = pk_bf16(sf[c * 2][mq][0],     sf[c * 2][mq][1]);
        aw[1] = pk_bf16(sf[c * 2][mq][2],     sf[c * 2][mq][3]);
        aw[2] = pk_bf16(sf[c * 2 + 1][mq][0], sf[c * 2 + 1][mq][1]);
        aw[3] = pk_bf16(sf[c * 2 + 1][mq][2], sf[c * 2 + 1][mq][3]);
        ap[mq] = __builtin_bit_cast(bf16x8, aw);
      }
      #pragma unroll
      for (int nt = 0; nt < 4; nt++){
        int rv = nt * 16 + l16;
        bf16x8 bv = as_bf(*(const u16x8*)&VTs[co + (rv << 6) + ((((c << 2) + quad) ^ (rv & 7)) << 3)]);
        #pragma unroll
        for (int mq = 0; mq < 2; mq++)
          acc[mq][nt] = __builtin_amdgcn_mfma_f32_16x16x32_bf16(ap[mq], bv, acc[mq][nt], 0, 0, 0);
      }
    }

    if (kt < 15){
      const int no = (co ^ 4096);
      *(u16x8*)&Ks[no + dofs0]  = kpre0;
      *(u16x8*)&Ks[no + dofs1]  = kpre1;
      *(u16x8*)&VTs[no + dofs0] = vpre0;
      *(u16x8*)&VTs[no + dofs1] = vpre1;
    }
    __syncthreads();
  }

  // ---- exact combine of the two KV halves through LDS (reuses K/V buffers) ----
  float* CBa = (float*)SM;                  // [32][256] acc partials (32KB)
  float* CBl = (float*)(SM + 16384);        // [2][256] li partials (2KB)
  const int gtid = tid & 255;
  if (grp == 1){
    #pragma unroll
    for (int mq = 0; mq < 2; mq++)
      #pragma unroll
      for (int nt = 0; nt < 4; nt++)
        #pragma unroll
        for (int r = 0; r < 4; r++)
          CBa[((mq * 4 + nt) * 4 + r) * 256 + gtid] = acc[mq][nt][r];
    CBl[gtid]       = li[0];
    CBl[256 + gtid] = li[1];
  }
  __syncthreads();
  if (grp == 1) return;

  #pragma unroll
  for (int mq = 0; mq < 2; mq++)
    #pragma unroll
    for (int nt = 0; nt < 4; nt++)
      #pragma unroll
      for (int r = 0; r < 4; r++)
        acc[mq][nt][r] += CBa[((mq * 4 + nt) * 4 + r) * 256 + gtid];
  li[0] += CBl[gtid];
  li[1] += CBl[256 + gtid];

  #pragma unroll
  for (int mq = 0; mq < 2; mq++){
    li[mq] += __shfl_xor(li[mq], 16);
    li[mq] += __shfl_xor(li[mq], 32);
  }
  float inv[2] = {1.0f / li[0], 1.0f / li[1]};
  float invr[2][4];
  #pragma unroll
  for (int mq = 0; mq < 2; mq++)
    #pragma unroll
    for (int r = 0; r < 4; r++)
      invr[mq][r] = __shfl(inv[mq], quad * 4 + r);

  int b = bh >> 4, h = bh & 15;
  #pragma unroll
  for (int mq = 0; mq < 2; mq++)
    #pragma unroll
    for (int nt = 0; nt < 4; nt++)
      #pragma unroll
      for (int r = 0; r < 4; r++){
        int s = qt * 128 + w * 32 + mq * 16 + quad * 4 + r;
        int d = h * 64 + nt * 16 + l16;
        o_ws[((size_t)(b * SEQ + s)) * EMBED + d] = f2bf(acc[mq][nt][r] * invr[mq][r]);
      }
}

// ---------------- launch ----------------
// ws alias table (40 MB):
//   [0,8M)   xb (prep-w, gemm_qkv-r; dead) -> o (attn-w, gemm_out-r)
//   [8,16M)  q      [16,24M) k     [24,32M) vt (gemm_qkv-w direct VT, attn-r)
//   [32,38M) wqkvT  [38,40M) woutT
extern "C" void kernel_launch(void* const* d_in, const int* in_sizes, int n_in,
                              void* d_out, int out_size, void* d_ws, size_t ws_size,
                              hipStream_t stream) {
  const float* x     = (const float*)d_in[0];
  const float* W_qkv = (const float*)d_in[1];
  const float* b_qkv = (const float*)d_in[2];
  const float* W_out = (const float*)d_in[3];
  const float* b_out = (const float*)d_in[4];
  float* out = (float*)d_out;

  char* ws = (char*)d_ws;
  unsigned short* xb    = (unsigned short*)(ws);
  unsigned short* o     = (unsigned short*)(ws);                      // reuses xb
  unsigned short* q     = (unsigned short*)(ws + ((size_t)8  << 20));
  unsigned short* k     = (unsigned short*)(ws + ((size_t)16 << 20));
  unsigned short* vt    = (unsigned short*)(ws + ((size_t)24 << 20));
  unsigned short* wqkvT = (unsigned short*)(ws + ((size_t)32 << 20));
  unsigned short* woutT = (unsigned short*)(ws + ((size_t)38 << 20));

  prep<<<dim3(8192), dim3(256), 0, stream>>>(x, xb, W_qkv, wqkvT, W_out, woutT);

  gemm_qkv<<<dim3(32, 24), dim3(256), 0, stream>>>(
      xb, wqkvT, b_qkv, q, k, vt, 4096, 3072, 1024);

  attn<<<dim3(512), dim3(512), 0, stream>>>(q, k, vt, o);

  gemm_out<<<dim3(32, 16), dim3(256), 0, stream>>>(
      o, woutT, b_out, out, 4096, 1024, 1024);
}

// Round 9
// 189.394 us; speedup vs baseline: 1.1129x; 1.0449x over previous
//
#include <hip/hip_runtime.h>
#include <stdint.h>
#include <math.h>

#define EMBED 1024
#define HEADS 16
#define HDIM  64
#define SEQ   2048
#define BATCH 2

typedef __bf16 bf16x8 __attribute__((ext_vector_type(8)));
typedef float  f32x4  __attribute__((ext_vector_type(4)));
typedef unsigned short u16x8 __attribute__((ext_vector_type(8)));
typedef unsigned short u16x4 __attribute__((ext_vector_type(4)));
typedef uint32_t u32x4v __attribute__((ext_vector_type(4)));

static __device__ __forceinline__ unsigned short f2bf(float f){
  union { float f; uint32_t u; } v; v.f = f;
  uint32_t u = v.u;
  uint32_t r = (u + 0x7FFFu + ((u >> 16) & 1u)) >> 16;  // RNE
  return (unsigned short)r;
}
static __device__ __forceinline__ bf16x8 as_bf(u16x8 v){ return __builtin_bit_cast(bf16x8, v); }

static __device__ __forceinline__ uint32_t pk_bf16(float a, float b){
#if defined(__has_builtin) && __has_builtin(__builtin_amdgcn_cvt_pk_bf16_f32)
  typedef __bf16 bf16x2 __attribute__((ext_vector_type(2)));
  bf16x2 p = __builtin_amdgcn_cvt_pk_bf16_f32(a, b);
  return __builtin_bit_cast(uint32_t, p);
#else
  return (uint32_t)f2bf(a) | ((uint32_t)f2bf(b) << 16);
#endif
}

static __device__ __forceinline__ float fexp2(float x){
#if defined(__has_builtin) && __has_builtin(__builtin_amdgcn_exp2f)
  return __builtin_amdgcn_exp2f(x);
#else
  return exp2f(x);
#endif
}

// async global->LDS, 16B per lane. lp_wave must be WAVE-UNIFORM; HW adds lane*16.
static __device__ __forceinline__ void stage16(const unsigned short* gp,
                                               unsigned short* lp_wave, int lane){
#if defined(__has_builtin) && __has_builtin(__builtin_amdgcn_global_load_lds)
  __builtin_amdgcn_global_load_lds((const __attribute__((address_space(1))) void*)gp,
                                   (__attribute__((address_space(3))) void*)lp_wave,
                                   16, 0, 0);
#else
  *(u16x8*)(lp_wave + lane * 8) = *(const u16x8*)gp;
#endif
}

// ---------------- prep: cast x -> bf16, W_qkv -> wqkvT, W_out -> woutT --------------
__global__ __launch_bounds__(256) void prep(
    const float* __restrict__ x,      unsigned short* __restrict__ xb,
    const float* __restrict__ W_qkv,  unsigned short* __restrict__ wqkvT,
    const float* __restrict__ W_out,  unsigned short* __restrict__ woutT)
{
  __shared__ unsigned short T[32 * 36];
  const int bid = blockIdx.x;
  const int t   = threadIdx.x;

  if (bid < 4096){
    int i = (bid * 256 + t) * 4;
    float4 v = *(const float4*)(x + i);
    u16x4 o;
    o[0] = f2bf(v.x); o[1] = f2bf(v.y); o[2] = f2bf(v.z); o[3] = f2bf(v.w);
    *(u16x4*)(xb + i) = o;
    return;
  }
  const float* W; unsigned short* Wt; int N, n0, k0;
  if (bid < 7168){
    int idx = bid - 4096;
    W = W_qkv; Wt = wqkvT; N = 3072;
    n0 = (idx % 96) * 32; k0 = (idx / 96) * 32;
  } else {
    int idx = bid - 7168;
    W = W_out; Wt = woutT; N = 1024;
    n0 = (idx & 31) * 32; k0 = (idx >> 5) * 32;
  }
  int kr = t >> 3, nc = (t & 7) * 4;
  float4 wv = *(const float4*)(W + (size_t)(k0 + kr) * N + n0 + nc);
  T[(nc + 0) * 36 + kr] = f2bf(wv.x);
  T[(nc + 1) * 36 + kr] = f2bf(wv.y);
  T[(nc + 2) * 36 + kr] = f2bf(wv.z);
  T[(nc + 3) * 36 + kr] = f2bf(wv.w);
  __syncthreads();
  int nr = t >> 3, kc = (t & 7) * 4;
  *(u16x4*)(Wt + (size_t)(n0 + nr) * 1024 + k0 + kc) = *(const u16x4*)&T[nr * 36 + kc];
}

// ---------------- QKV GEMM, BK=64; LDS-roundtrip coalesced epilogue -----------------
// Epilogue: stage the 128x128 bf16 tile into LDS (stride 136 u16 -> 16B-aligned
// rows, <=2-way banks), then 8 passes of u16x8 stores = full 128B-row coalescing
// for Q, K, and PV-permuted VT. Values identical to the scalar-store version.
__global__ __launch_bounds__(256) void gemm_qkv(
    const unsigned short* __restrict__ A,
    const unsigned short* __restrict__ Bt,
    const float* __restrict__ bias,
    unsigned short* __restrict__ q_ws,
    unsigned short* __restrict__ k_ws,
    unsigned short* __restrict__ vt_ws,
    int M, int N, int K)
{
  __shared__ unsigned short SM[128 * 136];  // 34.8KB; main loop uses first 32KB
  unsigned short* As = SM;                  // 128*64 u16
  unsigned short* Bs = SM + 8192;           // 128*64 u16
  const int tid  = threadIdx.x;
  const int bm   = blockIdx.x, bn = blockIdx.y;
  const int w    = tid >> 6, lane = tid & 63;
  const int quad = lane >> 4, l16 = lane & 15;
  const int wm   = (w >> 1) * 64, wn = (w & 1) * 64;

  f32x4 acc[4][4] = {};

  for (int k0 = 0; k0 < K; k0 += 64) {
    #pragma unroll
    for (int i = 0; i < 4; i++){
      int c = w * 4 + i;
      int row = c * 8 + (lane >> 3);
      int kg = (lane & 7) ^ (row & 7);
      stage16(A  + (size_t)(bm * 128 + row) * K + k0 + kg * 8, As + c * 512, lane);
      stage16(Bt + (size_t)(bn * 128 + row) * K + k0 + kg * 8, Bs + c * 512, lane);
    }
    __syncthreads();

    #pragma unroll
    for (int kk = 0; kk < 2; kk++){
      bf16x8 af[4], bfr[4];
      #pragma unroll
      for (int t = 0; t < 4; t++){
        int ra = wm + t * 16 + l16;
        int rb = wn + t * 16 + l16;
        af[t]  = as_bf(*(const u16x8*)&As[(ra << 6) + ((((kk << 2) + quad) ^ (ra & 7)) << 3)]);
        bfr[t] = as_bf(*(const u16x8*)&Bs[(rb << 6) + ((((kk << 2) + quad) ^ (rb & 7)) << 3)]);
      }
      #pragma unroll
      for (int mt = 0; mt < 4; mt++)
        #pragma unroll
        for (int nt = 0; nt < 4; nt++)
          acc[mt][nt] = __builtin_amdgcn_mfma_f32_16x16x32_bf16(af[mt], bfr[nt], acc[mt][nt], 0, 0, 0);
    }
    __syncthreads();
  }

  const int which = (bn * 128) >> 10;   // block-uniform: 0=Q 1=K 2=V
  const int b = bm >> 4;
  const int S0 = (bm & 15) * 128;

  // ---- stage tile to LDS (padded stride 136) ----
  if (which == 2){
    // V: T[n_local][spos_local] so read-out is contiguous along permuted s
    #pragma unroll
    for (int nt = 0; nt < 4; nt++){
      int coln = wn + nt * 16 + l16;
      float bv = bias[bn * 128 + coln];
      #pragma unroll
      for (int mt = 0; mt < 4; mt++){
        int sposl = wm + (mt >> 1) * 32 + quad * 8 + (mt & 1) * 4;
        #pragma unroll
        for (int r = 0; r < 4; r++)
          SM[coln * 136 + sposl + r] = f2bf(acc[mt][nt][r] + bv);
      }
    }
  } else {
    // Q/K: T[s_local][n_local] so read-out is contiguous along d
    const float scale = (which == 0) ? 0.18033688f : 1.0f;  // Q: 1/sqrt(Hd)*log2(e)
    #pragma unroll
    for (int nt = 0; nt < 4; nt++){
      int coln = wn + nt * 16 + l16;
      float bv = bias[bn * 128 + coln];
      #pragma unroll
      for (int mt = 0; mt < 4; mt++){
        int sl = wm + mt * 16 + quad * 4;
        #pragma unroll
        for (int r = 0; r < 4; r++)
          SM[(sl + r) * 136 + coln] = f2bf((acc[mt][nt][r] + bv) * scale);
      }
    }
  }
  __syncthreads();

  // ---- coalesced read-out: 8 passes x u16x8 per thread ----
  if (which == 2){
    #pragma unroll
    for (int p = 0; p < 8; p++){
      int nl = p * 16 + (tid >> 4);
      int s0 = (tid & 15) * 8;
      u16x8 v = *(const u16x8*)&SM[nl * 136 + s0];
      int ng = bn * 128 + nl;
      int h = (ng & 1023) >> 6, d = ng & 63;
      *(u16x8*)(vt_ws + (size_t)(b * HEADS + h) * SEQ * HDIM + (size_t)d * SEQ + S0 + s0) = v;
    }
  } else {
    unsigned short* dst = (which == 0) ? q_ws : k_ws;
    #pragma unroll
    for (int p = 0; p < 8; p++){
      int sl = p * 16 + (tid >> 4);
      int c0 = (tid & 15) * 8;
      u16x8 v = *(const u16x8*)&SM[sl * 136 + c0];
      int ng = bn * 128 + c0;
      int h = (ng & 1023) >> 6, d = ng & 63;
      *(u16x8*)(dst + (size_t)(b * HEADS + h) * SEQ * HDIM + (size_t)(S0 + sl) * HDIM + d) = v;
    }
  }
}

// ---------------- out-proj GEMM, BK=64: BM=128, BN=64 -------------------------------
__global__ __launch_bounds__(256) void gemm_out(
    const unsigned short* __restrict__ A,
    const unsigned short* __restrict__ Bt,
    const float* __restrict__ bias,
    float* __restrict__ Cout,
    int M, int N, int K)
{
  __shared__ unsigned short As[128 * 64];   // 16KB
  __shared__ unsigned short Bs[64 * 64];    // 8KB
  const int tid  = threadIdx.x;
  const int bm   = blockIdx.x, bn = blockIdx.y;
  const int w    = tid >> 6, lane = tid & 63;
  const int quad = lane >> 4, l16 = lane & 15;
  const int wm   = (w >> 1) * 64, wn = (w & 1) * 32;

  f32x4 acc[4][2] = {};

  for (int k0 = 0; k0 < K; k0 += 64) {
    #pragma unroll
    for (int i = 0; i < 4; i++){
      int c = w * 4 + i;
      int row = c * 8 + (lane >> 3);
      int kg = (lane & 7) ^ (row & 7);
      stage16(A + (size_t)(bm * 128 + row) * K + k0 + kg * 8, &As[c * 512], lane);
    }
    #pragma unroll
    for (int i = 0; i < 2; i++){
      int c = w * 2 + i;
      int row = c * 8 + (lane >> 3);
      int kg = (lane & 7) ^ (row & 7);
      stage16(Bt + (size_t)(bn * 64 + row) * K + k0 + kg * 8, &Bs[c * 512], lane);
    }
    __syncthreads();

    #pragma unroll
    for (int kk = 0; kk < 2; kk++){
      bf16x8 af[4], bfr[2];
      #pragma unroll
      for (int t = 0; t < 4; t++){
        int ra = wm + t * 16 + l16;
        af[t] = as_bf(*(const u16x8*)&As[(ra << 6) + ((((kk << 2) + quad) ^ (ra & 7)) << 3)]);
      }
      #pragma unroll
      for (int t = 0; t < 2; t++){
        int rb = wn + t * 16 + l16;
        bfr[t] = as_bf(*(const u16x8*)&Bs[(rb << 6) + ((((kk << 2) + quad) ^ (rb & 7)) << 3)]);
      }
      #pragma unroll
      for (int mt = 0; mt < 4; mt++)
        #pragma unroll
        for (int nt = 0; nt < 2; nt++)
          acc[mt][nt] = __builtin_amdgcn_mfma_f32_16x16x32_bf16(af[mt], bfr[nt], acc[mt][nt], 0, 0, 0);
    }
    __syncthreads();
  }

  #pragma unroll
  for (int mt = 0; mt < 4; mt++)
    #pragma unroll
    for (int nt = 0; nt < 2; nt++)
      #pragma unroll
      for (int r = 0; r < 4; r++){
        int gm = bm * 128 + wm + mt * 16 + quad * 4 + r;
        int gn = bn * 64 + wn + nt * 16 + l16;
        Cout[(size_t)gm * N + gn] = acc[mt][nt][r] + bias[gn];
      }
}

// ---------------- flash attention (exact R2: 512 thr, XCD swizzle, LDS dbuf) --------
__global__ __launch_bounds__(512) void attn(
    const unsigned short* __restrict__ q_ws,
    const unsigned short* __restrict__ k_ws,
    const unsigned short* __restrict__ vt_ws,
    unsigned short* __restrict__ o_ws)
{
  __shared__ unsigned short Qs[256 * 64];     // 32KB
  __shared__ unsigned short Ks[2][64 * 64];   // 16KB
  __shared__ unsigned short VTs[2][64 * 64];  // 16KB
  const int tid  = threadIdx.x;
  const int wgid = blockIdx.x;                 // [0,256)
  const int lin  = (wgid & 7) * 32 + (wgid >> 3);
  const int bh   = lin >> 3, qt = lin & 7;     // qt in [0,8): 256-row Q tile
  const int w    = tid >> 6, lane = tid & 63;
  const int quad = lane >> 4, l16 = lane & 15;
  const size_t base = (size_t)bh * SEQ * HDIM;

  #pragma unroll
  for (int i = 0; i < 4; i++){
    int c = w * 4 + i;
    int row = c * 8 + (lane >> 3);
    int kg = (lane & 7) ^ (row & 7);
    stage16(q_ws + base + (size_t)(qt * 256 + row) * HDIM + kg * 8, &Qs[c * 512], lane);
  }

  const int srow = w * 8 + (lane >> 3);
  const int skg  = (lane & 7) ^ (srow & 7);
  const int dofs = w * 512 + lane * 8;

  stage16(k_ws  + base + (size_t)srow * HDIM + skg * 8, &Ks[0][w * 512],  lane);
  stage16(vt_ws + base + (size_t)srow * SEQ + skg * 8,  &VTs[0][w * 512], lane);
  __syncthreads();

  bf16x8 bq[2][2];
  #pragma unroll
  for (int mq = 0; mq < 2; mq++){
    int row = w * 32 + mq * 16 + l16;
    #pragma unroll
    for (int ks = 0; ks < 2; ks++)
      bq[mq][ks] = as_bf(*(const u16x8*)&Qs[(row << 6) + ((((ks << 2) + quad) ^ (row & 7)) << 3)]);
  }

  const unsigned short* kp = k_ws  + base + (size_t)(64 + srow) * HDIM + skg * 8;
  const unsigned short* vp = vt_ws + base + (size_t)srow * SEQ + 64 + skg * 8;

  f32x4 acc[2][4] = {};
  float li[2] = {0.f, 0.f};

  for (int kt2 = 0; kt2 < SEQ / 128; kt2++){
    #pragma unroll
    for (int half = 0; half < 2; half++){
      const int cur = half;
      const int kt  = kt2 * 2 + half;
      u16x8 kpre, vpre;
      if (kt < SEQ / 64 - 1){
        kpre = *(const u16x8*)kp;  kp += 64 * HDIM;
        vpre = *(const u16x8*)vp;  vp += 64;
      }

      f32x4 sf[4][2] = {};
      #pragma unroll
      for (int ks = 0; ks < 2; ks++){
        #pragma unroll
        for (int nt = 0; nt < 4; nt++){
          int rk = nt * 16 + l16;
          bf16x8 ak = as_bf(*(const u16x8*)&Ks[cur][(rk << 6) + ((((ks << 2) + quad) ^ (rk & 7)) << 3)]);
          #pragma unroll
          for (int mq = 0; mq < 2; mq++)
            sf[nt][mq] = __builtin_amdgcn_mfma_f32_16x16x32_bf16(ak, bq[mq][ks], sf[nt][mq], 0, 0, 0);
        }
      }

      #pragma unroll
      for (int nt = 0; nt < 4; nt++)
        #pragma unroll
        for (int mq = 0; mq < 2; mq++)
          #pragma unroll
          for (int r = 0; r < 4; r++)
            sf[nt][mq][r] = fexp2(sf[nt][mq][r]);
      #pragma unroll
      for (int mq = 0; mq < 2; mq++)
        #pragma unroll
        for (int nt = 0; nt < 4; nt++)
          li[mq] += (sf[nt][mq][0] + sf[nt][mq][1]) + (sf[nt][mq][2] + sf[nt][mq][3]);

      #pragma unroll
      for (int c = 0; c < 2; c++){
        bf16x8 ap[2];
        #pragma unroll
        for (int mq = 0; mq < 2; mq++){
          u32x4v aw;
          aw[0] = pk_bf16(sf[c * 2][mq][0],     sf[c * 2][mq][1]);
          aw[1] = pk_bf16(sf[c * 2][mq][2],     sf[c * 2][mq][3]);
          aw[2] = pk_bf16(sf[c * 2 + 1][mq][0], sf[c * 2 + 1][mq][1]);
          aw[3] = pk_bf16(sf[c * 2 + 1][mq][2], sf[c * 2 + 1][mq][3]);
          ap[mq] = __builtin_bit_cast(bf16x8, aw);
        }
        #pragma unroll
        for (int nt = 0; nt < 4; nt++){
          int rv = nt * 16 + l16;
          bf16x8 bv = as_bf(*(const u16x8*)&VTs[cur][(rv << 6) + ((((c << 2) + quad) ^ (rv & 7)) << 3)]);
          #pragma unroll
          for (int mq = 0; mq < 2; mq++)
            acc[mq][nt] = __builtin_amdgcn_mfma_f32_16x16x32_bf16(ap[mq], bv, acc[mq][nt], 0, 0, 0);
        }
      }

      if (kt < SEQ / 64 - 1){
        *(u16x8*)&Ks[cur ^ 1][dofs]  = kpre;
        *(u16x8*)&VTs[cur ^ 1][dofs] = vpre;
      }
      __syncthreads();
    }
  }

  #pragma unroll
  for (int mq = 0; mq < 2; mq++){
    li[mq] += __shfl_xor(li[mq], 16);
    li[mq] += __shfl_xor(li[mq], 32);
  }
  float inv[2] = {1.0f / li[0], 1.0f / li[1]};
  float invr[2][4];
  #pragma unroll
  for (int mq = 0; mq < 2; mq++)
    #pragma unroll
    for (int r = 0; r < 4; r++)
      invr[mq][r] = __shfl(inv[mq], quad * 4 + r);

  int b = bh >> 4, h = bh & 15;
  #pragma unroll
  for (int mq = 0; mq < 2; mq++)
    #pragma unroll
    for (int nt = 0; nt < 4; nt++)
      #pragma unroll
      for (int r = 0; r < 4; r++){
        int s = qt * 256 + w * 32 + mq * 16 + quad * 4 + r;
        int d = h * 64 + nt * 16 + l16;
        o_ws[((size_t)(b * SEQ + s)) * EMBED + d] = f2bf(acc[mq][nt][r] * invr[mq][r]);
      }
}

// ---------------- launch ----------------
// ws alias table (40 MB):
//   [0,8M)   xb (prep-w, gemm_qkv-r; dead) -> o (attn-w, gemm_out-r)
//   [8,16M)  q      [16,24M) k     [24,32M) vt (gemm_qkv-w direct VT, attn-r)
//   [32,38M) wqkvT  [38,40M) woutT
extern "C" void kernel_launch(void* const* d_in, const int* in_sizes, int n_in,
                              void* d_out, int out_size, void* d_ws, size_t ws_size,
                              hipStream_t stream) {
  const float* x     = (const float*)d_in[0];
  const float* W_qkv = (const float*)d_in[1];
  const float* b_qkv = (const float*)d_in[2];
  const float* W_out = (const float*)d_in[3];
  const float* b_out = (const float*)d_in[4];
  float* out = (float*)d_out;

  char* ws = (char*)d_ws;
  unsigned short* xb    = (unsigned short*)(ws);
  unsigned short* o     = (unsigned short*)(ws);                      // reuses xb
  unsigned short* q     = (unsigned short*)(ws + ((size_t)8  << 20));
  unsigned short* k     = (unsigned short*)(ws + ((size_t)16 << 20));
  unsigned short* vt    = (unsigned short*)(ws + ((size_t)24 << 20));
  unsigned short* wqkvT = (unsigned short*)(ws + ((size_t)32 << 20));
  unsigned short* woutT = (unsigned short*)(ws + ((size_t)38 << 20));

  prep<<<dim3(8192), dim3(256), 0, stream>>>(x, xb, W_qkv, wqkvT, W_out, woutT);

  gemm_qkv<<<dim3(32, 24), dim3(256), 0, stream>>>(
      xb, wqkvT, b_qkv, q, k, vt, 4096, 3072, 1024);

  attn<<<dim3(256), dim3(512), 0, stream>>>(q, k, vt, o);

  gemm_out<<<dim3(32, 16), dim3(256), 0, stream>>>(
      o, woutT, b_out, out, 4096, 1024, 1024);
}

// Round 10
// 187.442 us; speedup vs baseline: 1.1245x; 1.0104x over previous
//
#include <hip/hip_runtime.h>
#include <stdint.h>
#include <math.h>

#define EMBED 1024
#define HEADS 16
#define HDIM  64
#define SEQ   2048
#define BATCH 2

typedef __bf16 bf16x8 __attribute__((ext_vector_type(8)));
typedef float  f32x4  __attribute__((ext_vector_type(4)));
typedef unsigned short u16x8 __attribute__((ext_vector_type(8)));
typedef unsigned short u16x4 __attribute__((ext_vector_type(4)));
typedef uint32_t u32x4v __attribute__((ext_vector_type(4)));

static __device__ __forceinline__ unsigned short f2bf(float f){
  union { float f; uint32_t u; } v; v.f = f;
  uint32_t u = v.u;
  uint32_t r = (u + 0x7FFFu + ((u >> 16) & 1u)) >> 16;  // RNE
  return (unsigned short)r;
}
static __device__ __forceinline__ bf16x8 as_bf(u16x8 v){ return __builtin_bit_cast(bf16x8, v); }

static __device__ __forceinline__ uint32_t pk_bf16(float a, float b){
#if defined(__has_builtin) && __has_builtin(__builtin_amdgcn_cvt_pk_bf16_f32)
  typedef __bf16 bf16x2 __attribute__((ext_vector_type(2)));
  bf16x2 p = __builtin_amdgcn_cvt_pk_bf16_f32(a, b);
  return __builtin_bit_cast(uint32_t, p);
#else
  return (uint32_t)f2bf(a) | ((uint32_t)f2bf(b) << 16);
#endif
}

static __device__ __forceinline__ float fexp2(float x){
#if defined(__has_builtin) && __has_builtin(__builtin_amdgcn_exp2f)
  return __builtin_amdgcn_exp2f(x);
#else
  return exp2f(x);
#endif
}

// async global->LDS, 16B per lane. lp_wave must be WAVE-UNIFORM; HW adds lane*16.
static __device__ __forceinline__ void stage16(const unsigned short* gp,
                                               unsigned short* lp_wave, int lane){
#if defined(__has_builtin) && __has_builtin(__builtin_amdgcn_global_load_lds)
  __builtin_amdgcn_global_load_lds((const __attribute__((address_space(1))) void*)gp,
                                   (__attribute__((address_space(3))) void*)lp_wave,
                                   16, 0, 0);
#else
  *(u16x8*)(lp_wave + lane * 8) = *(const u16x8*)gp;
#endif
}

// ---------------- prep: cast x -> bf16, W_qkv -> wqkvT, W_out -> woutT --------------
__global__ __launch_bounds__(256) void prep(
    const float* __restrict__ x,      unsigned short* __restrict__ xb,
    const float* __restrict__ W_qkv,  unsigned short* __restrict__ wqkvT,
    const float* __restrict__ W_out,  unsigned short* __restrict__ woutT)
{
  __shared__ unsigned short T[32 * 36];
  const int bid = blockIdx.x;
  const int t   = threadIdx.x;

  if (bid < 4096){
    int i = (bid * 256 + t) * 4;
    float4 v = *(const float4*)(x + i);
    u16x4 o;
    o[0] = f2bf(v.x); o[1] = f2bf(v.y); o[2] = f2bf(v.z); o[3] = f2bf(v.w);
    *(u16x4*)(xb + i) = o;
    return;
  }
  const float* W; unsigned short* Wt; int N, n0, k0;
  if (bid < 7168){
    int idx = bid - 4096;
    W = W_qkv; Wt = wqkvT; N = 3072;
    n0 = (idx % 96) * 32; k0 = (idx / 96) * 32;
  } else {
    int idx = bid - 7168;
    W = W_out; Wt = woutT; N = 1024;
    n0 = (idx & 31) * 32; k0 = (idx >> 5) * 32;
  }
  int kr = t >> 3, nc = (t & 7) * 4;
  float4 wv = *(const float4*)(W + (size_t)(k0 + kr) * N + n0 + nc);
  T[(nc + 0) * 36 + kr] = f2bf(wv.x);
  T[(nc + 1) * 36 + kr] = f2bf(wv.y);
  T[(nc + 2) * 36 + kr] = f2bf(wv.z);
  T[(nc + 3) * 36 + kr] = f2bf(wv.w);
  __syncthreads();
  int nr = t >> 3, kc = (t & 7) * 4;
  *(u16x4*)(Wt + (size_t)(n0 + nr) * 1024 + k0 + kc) = *(const u16x4*)&T[nr * 36 + kc];
}

// ---------------- QKV GEMM, BK=64; LDS-roundtrip coalesced epilogue (R9-proven) -----
__global__ __launch_bounds__(256) void gemm_qkv(
    const unsigned short* __restrict__ A,
    const unsigned short* __restrict__ Bt,
    const float* __restrict__ bias,
    unsigned short* __restrict__ q_ws,
    unsigned short* __restrict__ k_ws,
    unsigned short* __restrict__ vt_ws,
    int M, int N, int K)
{
  __shared__ unsigned short SM[128 * 136];  // 34.8KB; main loop uses first 32KB
  unsigned short* As = SM;                  // 128*64 u16
  unsigned short* Bs = SM + 8192;           // 128*64 u16
  const int tid  = threadIdx.x;
  const int bm   = blockIdx.x, bn = blockIdx.y;
  const int w    = tid >> 6, lane = tid & 63;
  const int quad = lane >> 4, l16 = lane & 15;
  const int wm   = (w >> 1) * 64, wn = (w & 1) * 64;

  f32x4 acc[4][4] = {};

  for (int k0 = 0; k0 < K; k0 += 64) {
    #pragma unroll
    for (int i = 0; i < 4; i++){
      int c = w * 4 + i;
      int row = c * 8 + (lane >> 3);
      int kg = (lane & 7) ^ (row & 7);
      stage16(A  + (size_t)(bm * 128 + row) * K + k0 + kg * 8, As + c * 512, lane);
      stage16(Bt + (size_t)(bn * 128 + row) * K + k0 + kg * 8, Bs + c * 512, lane);
    }
    __syncthreads();

    #pragma unroll
    for (int kk = 0; kk < 2; kk++){
      bf16x8 af[4], bfr[4];
      #pragma unroll
      for (int t = 0; t < 4; t++){
        int ra = wm + t * 16 + l16;
        int rb = wn + t * 16 + l16;
        af[t]  = as_bf(*(const u16x8*)&As[(ra << 6) + ((((kk << 2) + quad) ^ (ra & 7)) << 3)]);
        bfr[t] = as_bf(*(const u16x8*)&Bs[(rb << 6) + ((((kk << 2) + quad) ^ (rb & 7)) << 3)]);
      }
      #pragma unroll
      for (int mt = 0; mt < 4; mt++)
        #pragma unroll
        for (int nt = 0; nt < 4; nt++)
          acc[mt][nt] = __builtin_amdgcn_mfma_f32_16x16x32_bf16(af[mt], bfr[nt], acc[mt][nt], 0, 0, 0);
    }
    __syncthreads();
  }

  const int which = (bn * 128) >> 10;   // block-uniform: 0=Q 1=K 2=V
  const int b = bm >> 4;
  const int S0 = (bm & 15) * 128;

  if (which == 2){
    #pragma unroll
    for (int nt = 0; nt < 4; nt++){
      int coln = wn + nt * 16 + l16;
      float bv = bias[bn * 128 + coln];
      #pragma unroll
      for (int mt = 0; mt < 4; mt++){
        int sposl = wm + (mt >> 1) * 32 + quad * 8 + (mt & 1) * 4;
        #pragma unroll
        for (int r = 0; r < 4; r++)
          SM[coln * 136 + sposl + r] = f2bf(acc[mt][nt][r] + bv);
      }
    }
  } else {
    const float scale = (which == 0) ? 0.18033688f : 1.0f;  // Q: 1/sqrt(Hd)*log2(e)
    #pragma unroll
    for (int nt = 0; nt < 4; nt++){
      int coln = wn + nt * 16 + l16;
      float bv = bias[bn * 128 + coln];
      #pragma unroll
      for (int mt = 0; mt < 4; mt++){
        int sl = wm + mt * 16 + quad * 4;
        #pragma unroll
        for (int r = 0; r < 4; r++)
          SM[(sl + r) * 136 + coln] = f2bf((acc[mt][nt][r] + bv) * scale);
      }
    }
  }
  __syncthreads();

  if (which == 2){
    #pragma unroll
    for (int p = 0; p < 8; p++){
      int nl = p * 16 + (tid >> 4);
      int s0 = (tid & 15) * 8;
      u16x8 v = *(const u16x8*)&SM[nl * 136 + s0];
      int ng = bn * 128 + nl;
      int h = (ng & 1023) >> 6, d = ng & 63;
      *(u16x8*)(vt_ws + (size_t)(b * HEADS + h) * SEQ * HDIM + (size_t)d * SEQ + S0 + s0) = v;
    }
  } else {
    unsigned short* dst = (which == 0) ? q_ws : k_ws;
    #pragma unroll
    for (int p = 0; p < 8; p++){
      int sl = p * 16 + (tid >> 4);
      int c0 = (tid & 15) * 8;
      u16x8 v = *(const u16x8*)&SM[sl * 136 + c0];
      int ng = bn * 128 + c0;
      int h = (ng & 1023) >> 6, d = ng & 63;
      *(u16x8*)(dst + (size_t)(b * HEADS + h) * SEQ * HDIM + (size_t)(S0 + sl) * HDIM + d) = v;
    }
  }
}

// ---------------- out-proj GEMM, BK=64: BM=128, BN=64 -------------------------------
__global__ __launch_bounds__(256) void gemm_out(
    const unsigned short* __restrict__ A,
    const unsigned short* __restrict__ Bt,
    const float* __restrict__ bias,
    float* __restrict__ Cout,
    int M, int N, int K)
{
  __shared__ unsigned short As[128 * 64];   // 16KB
  __shared__ unsigned short Bs[64 * 64];    // 8KB
  const int tid  = threadIdx.x;
  const int bm   = blockIdx.x, bn = blockIdx.y;
  const int w    = tid >> 6, lane = tid & 63;
  const int quad = lane >> 4, l16 = lane & 15;
  const int wm   = (w >> 1) * 64, wn = (w & 1) * 32;

  f32x4 acc[4][2] = {};

  for (int k0 = 0; k0 < K; k0 += 64) {
    #pragma unroll
    for (int i = 0; i < 4; i++){
      int c = w * 4 + i;
      int row = c * 8 + (lane >> 3);
      int kg = (lane & 7) ^ (row & 7);
      stage16(A + (size_t)(bm * 128 + row) * K + k0 + kg * 8, &As[c * 512], lane);
    }
    #pragma unroll
    for (int i = 0; i < 2; i++){
      int c = w * 2 + i;
      int row = c * 8 + (lane >> 3);
      int kg = (lane & 7) ^ (row & 7);
      stage16(Bt + (size_t)(bn * 64 + row) * K + k0 + kg * 8, &Bs[c * 512], lane);
    }
    __syncthreads();

    #pragma unroll
    for (int kk = 0; kk < 2; kk++){
      bf16x8 af[4], bfr[2];
      #pragma unroll
      for (int t = 0; t < 4; t++){
        int ra = wm + t * 16 + l16;
        af[t] = as_bf(*(const u16x8*)&As[(ra << 6) + ((((kk << 2) + quad) ^ (ra & 7)) << 3)]);
      }
      #pragma unroll
      for (int t = 0; t < 2; t++){
        int rb = wn + t * 16 + l16;
        bfr[t] = as_bf(*(const u16x8*)&Bs[(rb << 6) + ((((kk << 2) + quad) ^ (rb & 7)) << 3)]);
      }
      #pragma unroll
      for (int mt = 0; mt < 4; mt++)
        #pragma unroll
        for (int nt = 0; nt < 2; nt++)
          acc[mt][nt] = __builtin_amdgcn_mfma_f32_16x16x32_bf16(af[mt], bfr[nt], acc[mt][nt], 0, 0, 0);
    }
    __syncthreads();
  }

  #pragma unroll
  for (int mt = 0; mt < 4; mt++)
    #pragma unroll
    for (int nt = 0; nt < 2; nt++)
      #pragma unroll
      for (int r = 0; r < 4; r++){
        int gm = bm * 128 + wm + mt * 16 + quad * 4 + r;
        int gn = bn * 64 + wn + nt * 16 + l16;
        Cout[(size_t)gm * N + gn] = acc[mt][nt][r] + bias[gn];
      }
}

// ---------------- flash attention: anti-phase wave-group pipeline -------------------
// R9 post-mortem: all prior structures keep waves in LOCKSTEP phases -> during the
// ~500cy exp2 segment both waves/SIMD contend for the trans pipe while MFMA idles,
// and vice versa; per-tile chain ~= SUM of phase lengths. Split 8 waves into:
//   group A (w 0-3): QK(t) -> softmax(t) -> PV(t)          [normal order]
//   group B (w 4-7): softmax(t-1) -> PV(t-1) -> QK(t)      [one stage behind]
// SIMD s hosts wave s (A) + wave s+4 (B) -> one wave issues MFMA while the other
// issues trans/VALU. B holds its V fragments in registers (loaded before the tile's
// buffer is recycled) -> no extra LDS, no race. Per-wave accumulation order is
// unchanged -> bitwise-identical output. Everything else identical to R9.
__global__ __launch_bounds__(512, 1) void attn(
    const unsigned short* __restrict__ q_ws,
    const unsigned short* __restrict__ k_ws,
    const unsigned short* __restrict__ vt_ws,
    unsigned short* __restrict__ o_ws)
{
  __shared__ unsigned short Qs[256 * 64];     // 32KB
  __shared__ unsigned short Ks[2][64 * 64];   // 16KB
  __shared__ unsigned short VTs[2][64 * 64];  // 16KB
  const int tid  = threadIdx.x;
  const int wgid = blockIdx.x;                 // [0,256)
  const int lin  = (wgid & 7) * 32 + (wgid >> 3);
  const int bh   = lin >> 3, qt = lin & 7;     // qt in [0,8): 256-row Q tile
  const int w    = tid >> 6, lane = tid & 63;
  const int quad = lane >> 4, l16 = lane & 15;
  const size_t base = (size_t)bh * SEQ * HDIM;

  #pragma unroll
  for (int i = 0; i < 4; i++){
    int c = w * 4 + i;
    int row = c * 8 + (lane >> 3);
    int kg = (lane & 7) ^ (row & 7);
    stage16(q_ws + base + (size_t)(qt * 256 + row) * HDIM + kg * 8, &Qs[c * 512], lane);
  }

  const int srow = w * 8 + (lane >> 3);
  const int skg  = (lane & 7) ^ (srow & 7);
  const int dofs = w * 512 + lane * 8;

  stage16(k_ws  + base + (size_t)srow * HDIM + skg * 8, &Ks[0][w * 512],  lane);
  stage16(vt_ws + base + (size_t)srow * SEQ + skg * 8,  &VTs[0][w * 512], lane);
  __syncthreads();

  bf16x8 bq[2][2];
  #pragma unroll
  for (int mq = 0; mq < 2; mq++){
    int row = w * 32 + mq * 16 + l16;
    #pragma unroll
    for (int ks = 0; ks < 2; ks++)
      bq[mq][ks] = as_bf(*(const u16x8*)&Qs[(row << 6) + ((((ks << 2) + quad) ^ (row & 7)) << 3)]);
  }

  const unsigned short* kp = k_ws  + base + (size_t)(64 + srow) * HDIM + skg * 8;
  const unsigned short* vp = vt_ws + base + (size_t)srow * SEQ + 64 + skg * 8;

  const bool grpB = (w >= 4);                  // wave-uniform

  f32x4 acc[2][4] = {};
  float li[2] = {0.f, 0.f};
  f32x4 sf[4][2];                              // B: carried across iterations
  bf16x8 bvB[2][4];                            // B: V frags carried in registers

  for (int kt = 0; kt < SEQ / 64; kt++){
    const int cur = kt & 1;
    const int co  = cur * 4096;
    u16x8 kpre, vpre;
    if (kt < SEQ / 64 - 1){
      kpre = *(const u16x8*)kp;  kp += 64 * HDIM;
      vpre = *(const u16x8*)vp;  vp += 64;
    }

    if (!grpB){
      // ---------- group A: QK(t) -> softmax(t) -> PV(t) ----------
      f32x4 sa[4][2] = {};
      #pragma unroll
      for (int ks = 0; ks < 2; ks++)
        #pragma unroll
        for (int nt = 0; nt < 4; nt++){
          int rk = nt * 16 + l16;
          bf16x8 ak = as_bf(*(const u16x8*)&Ks[0][co + (rk << 6) + ((((ks << 2) + quad) ^ (rk & 7)) << 3)]);
          #pragma unroll
          for (int mq = 0; mq < 2; mq++)
            sa[nt][mq] = __builtin_amdgcn_mfma_f32_16x16x32_bf16(ak, bq[mq][ks], sa[nt][mq], 0, 0, 0);
        }

      #pragma unroll
      for (int nt = 0; nt < 4; nt++)
        #pragma unroll
        for (int mq = 0; mq < 2; mq++)
          #pragma unroll
          for (int r = 0; r < 4; r++)
            sa[nt][mq][r] = fexp2(sa[nt][mq][r]);
      #pragma unroll
      for (int mq = 0; mq < 2; mq++)
        #pragma unroll
        for (int nt = 0; nt < 4; nt++)
          li[mq] += (sa[nt][mq][0] + sa[nt][mq][1]) + (sa[nt][mq][2] + sa[nt][mq][3]);

      #pragma unroll
      for (int c = 0; c < 2; c++){
        bf16x8 ap[2];
        #pragma unroll
        for (int mq = 0; mq < 2; mq++){
          u32x4v aw;
          aw[0] = pk_bf16(sa[c * 2][mq][0],     sa[c * 2][mq][1]);
          aw[1] = pk_bf16(sa[c * 2][mq][2],     sa[c * 2][mq][3]);
          aw[2] = pk_bf16(sa[c * 2 + 1][mq][0], sa[c * 2 + 1][mq][1]);
          aw[3] = pk_bf16(sa[c * 2 + 1][mq][2], sa[c * 2 + 1][mq][3]);
          ap[mq] = __builtin_bit_cast(bf16x8, aw);
        }
        #pragma unroll
        for (int nt = 0; nt < 4; nt++){
          int rv = nt * 16 + l16;
          bf16x8 bv = as_bf(*(const u16x8*)&VTs[0][co + (rv << 6) + ((((c << 2) + quad) ^ (rv & 7)) << 3)]);
          #pragma unroll
          for (int mq = 0; mq < 2; mq++)
            acc[mq][nt] = __builtin_amdgcn_mfma_f32_16x16x32_bf16(ap[mq], bv, acc[mq][nt], 0, 0, 0);
        }
      }
    } else {
      // ---------- group B: softmax(t-1) -> PV(t-1) [reg V] -> QK(t) -> load V(t) ----
      if (kt > 0){
        #pragma unroll
        for (int nt = 0; nt < 4; nt++)
          #pragma unroll
          for (int mq = 0; mq < 2; mq++)
            #pragma unroll
            for (int r = 0; r < 4; r++)
              sf[nt][mq][r] = fexp2(sf[nt][mq][r]);
        #pragma unroll
        for (int mq = 0; mq < 2; mq++)
          #pragma unroll
          for (int nt = 0; nt < 4; nt++)
            li[mq] += (sf[nt][mq][0] + sf[nt][mq][1]) + (sf[nt][mq][2] + sf[nt][mq][3]);

        #pragma unroll
        for (int c = 0; c < 2; c++){
          bf16x8 ap[2];
          #pragma unroll
          for (int mq = 0; mq < 2; mq++){
            u32x4v aw;
            aw[0] = pk_bf16(sf[c * 2][mq][0],     sf[c * 2][mq][1]);
            aw[1] = pk_bf16(sf[c * 2][mq][2],     sf[c * 2][mq][3]);
            aw[2] = pk_bf16(sf[c * 2 + 1][mq][0], sf[c * 2 + 1][mq][1]);
            aw[3] = pk_bf16(sf[c * 2 + 1][mq][2], sf[c * 2 + 1][mq][3]);
            ap[mq] = __builtin_bit_cast(bf16x8, aw);
          }
          #pragma unroll
          for (int nt = 0; nt < 4; nt++)
            #pragma unroll
            for (int mq = 0; mq < 2; mq++)
              acc[mq][nt] = __builtin_amdgcn_mfma_f32_16x16x32_bf16(ap[mq], bvB[c][nt], acc[mq][nt], 0, 0, 0);
        }
      }

      #pragma unroll
      for (int nt = 0; nt < 4; nt++)
        #pragma unroll
        for (int mq = 0; mq < 2; mq++)
          sf[nt][mq] = f32x4{0.f, 0.f, 0.f, 0.f};
      #pragma unroll
      for (int ks = 0; ks < 2; ks++)
        #pragma unroll
        for (int nt = 0; nt < 4; nt++){
          int rk = nt * 16 + l16;
          bf16x8 ak = as_bf(*(const u16x8*)&Ks[0][co + (rk << 6) + ((((ks << 2) + quad) ^ (rk & 7)) << 3)]);
          #pragma unroll
          for (int mq = 0; mq < 2; mq++)
            sf[nt][mq] = __builtin_amdgcn_mfma_f32_16x16x32_bf16(ak, bq[mq][ks], sf[nt][mq], 0, 0, 0);
        }

      #pragma unroll
      for (int c = 0; c < 2; c++)
        #pragma unroll
        for (int nt = 0; nt < 4; nt++){
          int rv = nt * 16 + l16;
          bvB[c][nt] = as_bf(*(const u16x8*)&VTs[0][co + (rv << 6) + ((((c << 2) + quad) ^ (rv & 7)) << 3)]);
        }
    }

    if (kt < SEQ / 64 - 1){
      const int no = co ^ 4096;
      *(u16x8*)&Ks[0][no + dofs]  = kpre;
      *(u16x8*)&VTs[0][no + dofs] = vpre;
    }
    __syncthreads();
  }

  // ---------- group B: drain final tile ----------
  if (grpB){
    #pragma unroll
    for (int nt = 0; nt < 4; nt++)
      #pragma unroll
      for (int mq = 0; mq < 2; mq++)
        #pragma unroll
        for (int r = 0; r < 4; r++)
          sf[nt][mq][r] = fexp2(sf[nt][mq][r]);
    #pragma unroll
    for (int mq = 0; mq < 2; mq++)
      #pragma unroll
      for (int nt = 0; nt < 4; nt++)
        li[mq] += (sf[nt][mq][0] + sf[nt][mq][1]) + (sf[nt][mq][2] + sf[nt][mq][3]);
    #pragma unroll
    for (int c = 0; c < 2; c++){
      bf16x8 ap[2];
      #pragma unroll
      for (int mq = 0; mq < 2; mq++){
        u32x4v aw;
        aw[0] = pk_bf16(sf[c * 2][mq][0],     sf[c * 2][mq][1]);
        aw[1] = pk_bf16(sf[c * 2][mq][2],     sf[c * 2][mq][3]);
        aw[2] = pk_bf16(sf[c * 2 + 1][mq][0], sf[c * 2 + 1][mq][1]);
        aw[3] = pk_bf16(sf[c * 2 + 1][mq][2], sf[c * 2 + 1][mq][3]);
        ap[mq] = __builtin_bit_cast(bf16x8, aw);
      }
      #pragma unroll
      for (int nt = 0; nt < 4; nt++)
        #pragma unroll
        for (int mq = 0; mq < 2; mq++)
          acc[mq][nt] = __builtin_amdgcn_mfma_f32_16x16x32_bf16(ap[mq], bvB[c][nt], acc[mq][nt], 0, 0, 0);
    }
  }

  #pragma unroll
  for (int mq = 0; mq < 2; mq++){
    li[mq] += __shfl_xor(li[mq], 16);
    li[mq] += __shfl_xor(li[mq], 32);
  }
  float inv[2] = {1.0f / li[0], 1.0f / li[1]};
  float invr[2][4];
  #pragma unroll
  for (int mq = 0; mq < 2; mq++)
    #pragma unroll
    for (int r = 0; r < 4; r++)
      invr[mq][r] = __shfl(inv[mq], quad * 4 + r);

  int b = bh >> 4, h = bh & 15;
  #pragma unroll
  for (int mq = 0; mq < 2; mq++)
    #pragma unroll
    for (int nt = 0; nt < 4; nt++)
      #pragma unroll
      for (int r = 0; r < 4; r++){
        int s = qt * 256 + w * 32 + mq * 16 + quad * 4 + r;
        int d = h * 64 + nt * 16 + l16;
        o_ws[((size_t)(b * SEQ + s)) * EMBED + d] = f2bf(acc[mq][nt][r] * invr[mq][r]);
      }
}

// ---------------- launch ----------------
// ws alias table (40 MB):
//   [0,8M)   xb (prep-w, gemm_qkv-r; dead) -> o (attn-w, gemm_out-r)
//   [8,16M)  q      [16,24M) k     [24,32M) vt (gemm_qkv-w direct VT, attn-r)
//   [32,38M) wqkvT  [38,40M) woutT
extern "C" void kernel_launch(void* const* d_in, const int* in_sizes, int n_in,
                              void* d_out, int out_size, void* d_ws, size_t ws_size,
                              hipStream_t stream) {
  const float* x     = (const float*)d_in[0];
  const float* W_qkv = (const float*)d_in[1];
  const float* b_qkv = (const float*)d_in[2];
  const float* W_out = (const float*)d_in[3];
  const float* b_out = (const float*)d_in[4];
  float* out = (float*)d_out;

  char* ws = (char*)d_ws;
  unsigned short* xb    = (unsigned short*)(ws);
  unsigned short* o     = (unsigned short*)(ws);                      // reuses xb
  unsigned short* q     = (unsigned short*)(ws + ((size_t)8  << 20));
  unsigned short* k     = (unsigned short*)(ws + ((size_t)16 << 20));
  unsigned short* vt    = (unsigned short*)(ws + ((size_t)24 << 20));
  unsigned short* wqkvT = (unsigned short*)(ws + ((size_t)32 << 20));
  unsigned short* woutT = (unsigned short*)(ws + ((size_t)38 << 20));

  prep<<<dim3(8192), dim3(256), 0, stream>>>(x, xb, W_qkv, wqkvT, W_out, woutT);

  gemm_qkv<<<dim3(32, 24), dim3(256), 0, stream>>>(
      xb, wqkvT, b_qkv, q, k, vt, 4096, 3072, 1024);

  attn<<<dim3(256), dim3(512), 0, stream>>>(q, k, vt, o);

  gemm_out<<<dim3(32, 16), dim3(256), 0, stream>>>(
      o, woutT, b_out, out, 4096, 1024, 1024);
}